// Round 1
// 635.956 us; speedup vs baseline: 1.0089x; 1.0089x over previous
//
#include <hip/hip_runtime.h>

// SimplifiedHAFE on MI355X — round 7: wide gathers + staged-load pipelining.
//  (a) k_gat1/k_gat2 aggregation reworked: 4 edges per wave-iteration with
//      dwordx4 (gat1) / dwordx2 (gat2) gathers. VMEM instrs per edge drop
//      4x (2 -> 0.5), address/unpack VALU per edge ~2x. Cross-group (g=
//      lane>>4) sums folded with 2 shfl_xor steps; LN stats scaled by 1/4
//      for the 4x duplication.
//  (b) k_fe1 / k_prep_gemm A-staging software-pipelined: chunk k+1's global
//      loads issue between the LDS write and the MFMA barrier, hiding HBM
//      latency under the MFMA phase (T14 async-split).
//  (c) As before: all GEMM B matrices pre-swizzled to MFMA-fragment-order
//      bf16; A converts fp32->bf16 via v_perm pack; gat CSR with packed
//      type bits.

#define LRELU(x) ((x) > 0.f ? (x) : 0.2f * (x))

typedef __attribute__((ext_vector_type(8))) short short8;
typedef __attribute__((ext_vector_type(4))) float floatx4;

__device__ __forceinline__ unsigned short f2bf(float x) {
    union { float f; unsigned int u; } v; v.f = x;
    unsigned int r = (v.u + 0x7FFFu + ((v.u >> 16) & 1u)) >> 16;  // RNE
    return (unsigned short)r;
}
// pack 2 fp32 -> 2 bf16 (round-half-up) in ~3 VALU via v_perm_b32
__device__ __forceinline__ unsigned int pkbf(float lo, float hi) {
    unsigned int a = __float_as_uint(lo) + 0x8000u;
    unsigned int b = __float_as_uint(hi) + 0x8000u;
    return __builtin_amdgcn_perm(b, a, 0x07060302u);
}
__device__ __forceinline__ float bflo(unsigned int u) {
    return __uint_as_float(u << 16);
}
__device__ __forceinline__ float bfhi(unsigned int u) {
    return __uint_as_float(u & 0xFFFF0000u);
}
__device__ __forceinline__ float bf1(unsigned short u) {
    return __uint_as_float(((unsigned int)u) << 16);
}

// ---------------------------------------------------------------- tiny tables
__global__ __launch_bounds__(64) void k_tables(
    const float* __restrict__ e_emb1, const float* __restrict__ lew1,
    const float* __restrict__ ae1,
    const float* __restrict__ e_emb2, const float* __restrict__ lew2,
    const float* __restrict__ ae2,
    float* __restrict__ aet1, float* __restrict__ aet2)
{
    __shared__ float M1[16];
    __shared__ float M2[4];
    int t = threadIdx.x;
    if (t < 16) {
        int d = t >> 2, h = t & 3;
        float s = 0.f;
        for (int c = 0; c < 64; ++c) s += lew1[d * 256 + h * 64 + c] * ae1[h * 64 + c];
        M1[d * 4 + h] = s;
    }
    if (t < 4) {
        float s = 0.f;
        for (int c = 0; c < 64; ++c) s += lew2[t * 64 + c] * ae2[c];
        M2[t] = s;
    }
    __syncthreads();
    if (t < 16) {
        int ty = t >> 2, h = t & 3;
        float s = 0.f;
        for (int d = 0; d < 4; ++d) s += e_emb1[ty * 4 + d] * M1[d * 4 + h];
        aet1[ty * 4 + h] = s;
    }
    if (t < 4) {
        float s = 0.f;
        for (int d = 0; d < 4; ++d) s += e_emb2[t * 4 + d] * M2[d];
        aet2[t] = s;
    }
}

// ----------------- B pre-swizzle: fe1 weight (768x64) -> frag-order bf16
__global__ __launch_bounds__(256) void k_bswz_fe1(
    const float* __restrict__ w1, unsigned short* __restrict__ out)
{
    for (int idx = blockIdx.x * 256 + threadIdx.x; idx < 768 * 64;
         idx += gridDim.x * 256) {
        int k = idx >> 6, col = idx & 63;
        int c = k >> 6, kl = k & 63, kg = kl >> 3, j = kl & 7;
        out[((c * 8 + kg) * 64 + col) * 8 + j] = f2bf(w1[k * 64 + col]);
    }
}

// --------- B pre-swizzle: concat [B1|B2] (Kx2NH) -> frag-order, 128-col tiles
template<int K, int NH>
__global__ __launch_bounds__(256) void k_bswz2(
    const float* __restrict__ B1, const float* __restrict__ B2,
    unsigned short* __restrict__ out)
{
    const int NC = 2 * NH;
    for (int idx = blockIdx.x * 256 + threadIdx.x; idx < K * NC;
         idx += gridDim.x * 256) {
        int k = idx / NC, col = idx % NC;
        float v = (col < NH) ? B1[k * NH + col] : B2[k * NH + col - NH];
        int c = k >> 6, kl = k & 63, kg = kl >> 3, j = kl & 7;
        int ct = col >> 7, cl = col & 127;
        out[(((c * (NC / 128) + ct) * 8 + kg) * 128 + cl) * 8 + j] = f2bf(v);
    }
}

// ------------------ FE stage 1: relu(X@W1+b1), bf16 MFMA, pre-swizzled B
__global__ __launch_bounds__(256) void k_fe1(
    const float* __restrict__ feat, const unsigned short* __restrict__ bswz,
    const float* __restrict__ b1, float* __restrict__ t1, int N)
{
    __shared__ __align__(16) unsigned short A_lds[8 * 64 * 8];  // 8 KiB
    int t = threadIdx.x;
    int wv = t >> 6, lane = t & 63;
    int quad = lane >> 4, l16 = lane & 15;
    long n0 = (long)blockIdx.x * 64;

    floatx4 acc[4];
#pragma unroll
    for (int i = 0; i < 4; ++i) acc[i] = (floatx4){0.f, 0.f, 0.f, 0.f};

    int srow = t >> 2, sf4 = t & 3;
    long arow = n0 + srow;
    if (arow >= N) arow = N - 1;
    const float* fbase = feat + arow * 768 + sf4 * 16;
    int col = wv * 16 + l16;

    // prologue: load chunk 0
    float4 v0 = *(const float4*)(fbase);
    float4 v1 = *(const float4*)(fbase + 4);
    float4 v2 = *(const float4*)(fbase + 8);
    float4 v3 = *(const float4*)(fbase + 12);

    for (int kc = 0; kc < 768; kc += 64) {
        uint4 w0 = {pkbf(v0.x, v0.y), pkbf(v0.z, v0.w),
                    pkbf(v1.x, v1.y), pkbf(v1.z, v1.w)};
        uint4 w1p = {pkbf(v2.x, v2.y), pkbf(v2.z, v2.w),
                     pkbf(v3.x, v3.y), pkbf(v3.z, v3.w)};
        __syncthreads();  // prev chunk's MFMA readers done
        *(uint4*)&A_lds[((2 * sf4) * 64 + srow) * 8] = w0;
        *(uint4*)&A_lds[((2 * sf4 + 1) * 64 + srow) * 8] = w1p;
        if (kc + 64 < 768) {  // prefetch next chunk; latency hides under MFMA
            v0 = *(const float4*)(fbase + kc + 64);
            v1 = *(const float4*)(fbase + kc + 68);
            v2 = *(const float4*)(fbase + kc + 72);
            v3 = *(const float4*)(fbase + kc + 76);
        }
        __syncthreads();
        int ci = kc >> 6;
#pragma unroll
        for (int s = 0; s < 2; ++s) {
            int kg0 = s * 4 + quad;
            short8 bfrag = *(const short8*)&bswz[((ci * 8 + kg0) * 64 + col) * 8];
#pragma unroll
            for (int mt = 0; mt < 4; ++mt) {
                short8 afrag = *(const short8*)&A_lds[(kg0 * 64 + mt * 16 + l16) * 8];
                acc[mt] = __builtin_amdgcn_mfma_f32_16x16x32_bf16(
                    afrag, bfrag, acc[mt], 0, 0, 0);
            }
        }
    }
    float bb = b1[col];
#pragma unroll
    for (int mt = 0; mt < 4; ++mt) {
#pragma unroll
        for (int r = 0; r < 4; ++r) {
            long m = n0 + mt * 16 + quad * 4 + r;
            if (m < N) t1[m * 64 + col] = fmaxf(acc[mt][r] + bb, 0.f);
        }
    }
}

// ------------------------- FE tail: (@W2+b2 + emb + pos terms) @ out_w + b
__global__ __launch_bounds__(256) void k_fe2(
    const float* __restrict__ t1, const float* __restrict__ w2,
    const float* __restrict__ b2, const int* __restrict__ ntypes,
    const float* __restrict__ temb, const float* __restrict__ pos,
    const float* __restrict__ posw, const float* __restrict__ posb,
    const float* __restrict__ outw, const float* __restrict__ outb,
    float* __restrict__ hfe)
{
    __shared__ float l1[256];
    __shared__ float l2[256];
    int t = threadIdx.x;
    long base = (long)blockIdx.x * 256;
    l1[t] = t1[base + t];
    __syncthreads();
    int r = t >> 6, c = t & 63;
    float acc = 0.f;
#pragma unroll 8
    for (int k = 0; k < 64; ++k) acc += l1[r * 64 + k] * w2[k * 64 + c];
    long n = (long)blockIdx.x * 4 + r;
    int nt = ntypes[n];
    acc += b2[c] + temb[nt * 64 + c] + pos[n] * posw[c] + posb[c];
    l2[r * 64 + c] = acc;
    __syncthreads();
    float acc2 = 0.f;
#pragma unroll 8
    for (int k = 0; k < 64; ++k) acc2 += l2[r * 64 + k] * outw[k * 64 + c];
    hfe[n * 64 + c] = acc2 + outb[c];
}

// ------- prep GEMM: A[NxK] @ preswizzled [B1|B2][Kx2NH] -> xs bf16 + res fp32
template<int K, int NH>
__global__ __launch_bounds__(256) void k_prep_gemm(
    const float* __restrict__ A, const unsigned short* __restrict__ bswz,
    const float* __restrict__ bias, const float* __restrict__ res_b,
    unsigned short* __restrict__ xsb, float* __restrict__ resp, int N)
{
    constexpr int CT = (2 * NH) / 128;
    __shared__ __align__(16) unsigned short A_lds[8 * 64 * 8];  // 8 KB
    int t = threadIdx.x;
    int wv = t >> 6, lane = t & 63;
    int quad = lane >> 4, l16 = lane & 15;
    long n0 = (long)blockIdx.x * 64;
    int by = blockIdx.y;

    floatx4 acc[4][2];
#pragma unroll
    for (int i = 0; i < 4; ++i)
#pragma unroll
        for (int j = 0; j < 2; ++j) acc[i][j] = (floatx4){0.f, 0.f, 0.f, 0.f};

    int srow = t >> 2, sf4 = t & 3;
    long arow = n0 + srow;
    if (arow >= N) arow = N - 1;
    const float* abase = A + arow * (long)K + sf4 * 16;

    // prologue: load chunk 0
    float4 v0 = *(const float4*)(abase);
    float4 v1 = *(const float4*)(abase + 4);
    float4 v2 = *(const float4*)(abase + 8);
    float4 v3 = *(const float4*)(abase + 12);

    for (int kc = 0; kc < K; kc += 64) {
        uint4 w0 = {pkbf(v0.x, v0.y), pkbf(v0.z, v0.w),
                    pkbf(v1.x, v1.y), pkbf(v1.z, v1.w)};
        uint4 w1p = {pkbf(v2.x, v2.y), pkbf(v2.z, v2.w),
                     pkbf(v3.x, v3.y), pkbf(v3.z, v3.w)};
        __syncthreads();
        *(uint4*)&A_lds[((2 * sf4) * 64 + srow) * 8] = w0;
        *(uint4*)&A_lds[((2 * sf4 + 1) * 64 + srow) * 8] = w1p;
        if (kc + 64 < K) {
            v0 = *(const float4*)(abase + kc + 64);
            v1 = *(const float4*)(abase + kc + 68);
            v2 = *(const float4*)(abase + kc + 72);
            v3 = *(const float4*)(abase + kc + 76);
        }
        __syncthreads();
        int ci = kc >> 6;
#pragma unroll
        for (int s = 0; s < 2; ++s) {
            int kg0 = s * 4 + quad;
#pragma unroll
            for (int nt = 0; nt < 2; ++nt) {
                short8 bfrag = *(const short8*)&bswz[
                    (((ci * CT + by) * 8 + kg0) * 128 + wv * 32 + nt * 16 + l16) * 8];
#pragma unroll
                for (int mt = 0; mt < 4; ++mt) {
                    short8 afrag = *(const short8*)&A_lds[(kg0 * 64 + mt * 16 + l16) * 8];
                    acc[mt][nt] = __builtin_amdgcn_mfma_f32_16x16x32_bf16(
                        afrag, bfrag, acc[mt][nt], 0, 0, 0);
                }
            }
        }
    }
#pragma unroll
    for (int nt = 0; nt < 2; ++nt) {
        int gc = by * 128 + wv * 32 + nt * 16 + l16;
        bool isl = gc < NH;
        int oc = isl ? gc : gc - NH;
        float badd = isl ? 0.f : (bias[oc] + res_b[oc]);
#pragma unroll
        for (int mt = 0; mt < 4; ++mt) {
#pragma unroll
            for (int r = 0; r < 4; ++r) {
                long m = n0 + mt * 16 + quad * 4 + r;
                if (m < N) {
                    float val = acc[mt][nt][r];
                    if (isl) xsb[m * NH + oc] = f2bf(val);
                    else     resp[m * NH + oc] = val + badd;
                }
            }
        }
    }
}

// --------- attention scalars: a_src/a_dst[n,h] = dot(xs[n,h*64:+64], att)
template<int H>
__global__ __launch_bounds__(256) void k_att(
    const unsigned short* __restrict__ xsb, const float* __restrict__ att_s,
    const float* __restrict__ att_d, float* __restrict__ a_src,
    float* __restrict__ a_dst, int N)
{
    int t = threadIdx.x;
    int wv = t >> 6, lane = t & 63;
    long n = (long)blockIdx.x * 4 + wv;
    if (n >= N) return;
    if (H == 4) {
        ushort4 u = *(const ushort4*)&xsb[n * 256 + lane * 4];
        float4 as = *(const float4*)&att_s[lane * 4];
        float4 ad = *(const float4*)&att_d[lane * 4];
        float x0 = bf1(u.x), x1 = bf1(u.y), x2 = bf1(u.z), x3 = bf1(u.w);
        float p = x0 * as.x + x1 * as.y + x2 * as.z + x3 * as.w;
        float q = x0 * ad.x + x1 * ad.y + x2 * ad.z + x3 * ad.w;
#pragma unroll
        for (int k = 8; k; k >>= 1) {
            p += __shfl_xor(p, k, 64);
            q += __shfl_xor(q, k, 64);
        }
        if ((lane & 15) == 0) {
            a_src[n * 4 + (lane >> 4)] = p;
            a_dst[n * 4 + (lane >> 4)] = q;
        }
    } else {
        float x = bf1(xsb[n * 64 + lane]);
        float p = x * att_s[lane];
        float q = x * att_d[lane];
#pragma unroll
        for (int k = 32; k; k >>= 1) {
            p += __shfl_xor(p, k, 64);
            q += __shfl_xor(q, k, 64);
        }
        if (lane == 0) { a_src[n] = p; a_dst[n] = q; }
    }
}

// ---------------------------------------------------------------- CSR build
__global__ __launch_bounds__(256) void k_count(
    const int* __restrict__ dst, const int* __restrict__ et,
    int* __restrict__ cnt_t, int E)
{
    int e = blockIdx.x * 256 + threadIdx.x;
    if (e < E) atomicAdd(&cnt_t[dst[e] * 4 + et[e]], 1);
}

__global__ __launch_bounds__(256) void k_scan1(
    const int* __restrict__ cnt_t, int* __restrict__ row_off,
    int* __restrict__ blk_sums, int N)
{
    __shared__ int s[256];
    int t = threadIdx.x;
    int i = blockIdx.x * 256 + t;
    int v = 0;
    if (i < N) v = cnt_t[4 * i] + cnt_t[4 * i + 1] + cnt_t[4 * i + 2] + cnt_t[4 * i + 3];
    s[t] = v;
    __syncthreads();
    for (int off = 1; off < 256; off <<= 1) {
        int x = 0;
        if (t >= off) x = s[t - off];
        __syncthreads();
        s[t] += x;
        __syncthreads();
    }
    if (i < N) row_off[i] = s[t] - v;
    if (t == 255) blk_sums[blockIdx.x] = s[255];
}

__global__ __launch_bounds__(256) void k_scan2(int* __restrict__ blk_sums, int nb)
{
    __shared__ int s[256];
    int t = threadIdx.x;
    int v = (t < nb) ? blk_sums[t] : 0;
    s[t] = v;
    __syncthreads();
    for (int off = 1; off < 256; off <<= 1) {
        int x = 0;
        if (t >= off) x = s[t - off];
        __syncthreads();
        s[t] += x;
        __syncthreads();
    }
    if (t < nb) blk_sums[t] = s[t] - v;
}

__global__ __launch_bounds__(256) void k_scan3(
    int* __restrict__ row_off, int* __restrict__ cursor,
    const int* __restrict__ blk_sums, int N, int E)
{
    int t = threadIdx.x;
    int i = blockIdx.x * 256 + t;
    if (i < N) {
        int o = row_off[i] + blk_sums[blockIdx.x];
        row_off[i] = o;
        cursor[i] = o;
    }
    if (i == 0) row_off[N] = E;
}

__global__ __launch_bounds__(256) void k_scatter(
    const int* __restrict__ src, const int* __restrict__ dst,
    const int* __restrict__ et, int* __restrict__ cursor,
    int* __restrict__ csr_pack, int E)
{
    int e = blockIdx.x * 256 + threadIdx.x;
    if (e < E) {
        int d = dst[e];
        int pos = atomicAdd(&cursor[d], 1);
        csr_pack[pos] = src[e] | (et[e] << 28);
    }
}

// ---------------- GAT layer 1: 128 thr = 2 waves; wave w owns heads 2w,2w+1.
// Gather phase: 4 edges / wave-iter, each covered by 16 lanes x dwordx4
// (8 bf16 cols per lane). g = lane>>4 selects the edge, lc = lane&15 the
// column slice. Cross-g partial sums folded via shfl_xor(16/32); LN stats
// carry a 4x duplication factor (scaled by 0.25).
__global__ __launch_bounds__(128) void k_gat1(
    const unsigned short* __restrict__ xs1b, const float* __restrict__ a_src,
    const float* __restrict__ a_dst, const int* __restrict__ row_off,
    const int* __restrict__ csr_pack,
    const int* __restrict__ cnt_t, const float* __restrict__ aet1,
    const float* __restrict__ ln_g, const float* __restrict__ ln_b,
    float* io)
{
    __shared__ __align__(16) float4 ws[2][64];
    __shared__ float2 aetp[2][4];
    __shared__ float red[4];
    int n = blockIdx.x;
    int t = threadIdx.x;
    int w = t >> 6, c = t & 63;
    int lc = c & 15, g = c >> 4;
    int h0 = 2 * w;
    if (t < 8) {
        int w2 = t >> 2, ty = t & 3;
        aetp[w2][ty] = make_float2(aet1[ty * 4 + 2 * w2], aet1[ty * 4 + 2 * w2 + 1]);
    }
    int off = row_off[n], deg = row_off[n + 1] - off;
    float2 a_d = *(const float2*)&a_dst[n * 4 + h0];
    __syncthreads();
    float ael0 = 0.f, ael1 = 0.f;
    int degc = 0;
#pragma unroll
    for (int ty = 0; ty < 4; ++ty) {
        int ct = cnt_t[n * 4 + ty];
        degc += ct;
        float2 ae = aetp[w][ty];
        ael0 += (float)ct * ae.x;
        ael1 += (float)ct * ae.y;
    }
    float inv = (degc > 0) ? 1.f / (float)degc : 1.f;
    float2 a_s_self = *(const float2*)&a_src[n * 4 + h0];
    float al0 = a_s_self.x + a_d.x + ael0 * inv;
    float al1 = a_s_self.y + a_d.y + ael1 * inv;
    al0 = LRELU(al0); al1 = LRELU(al1);
    float wself0 = expf(al0), wself1 = expf(al1);

    int col0 = w * 128 + lc * 8;                    // 8 cols per lane
    const unsigned short* xrow = xs1b + col0;       // + s*256 per gather
    float acc[8];
#pragma unroll
    for (int j = 0; j < 8; ++j) acc[j] = 0.f;
    float dp0 = 0.f, dp1 = 0.f;

    for (int base = 0; base < deg; base += 64) {
        int cnt = min(64, deg - base);
        float w0 = 0.f, w1 = 0.f;
        int s = 0;
        if (c < cnt) {
            int pk = csr_pack[off + base + c];
            s = pk & 0x0FFFFFFF;
            int ty = ((unsigned)pk) >> 28;
            float2 as2 = *(const float2*)&a_src[s * 4 + h0];
            float2 ae = aetp[w][ty];
            float a0 = as2.x + a_d.x + ae.x;
            float a1 = as2.y + a_d.y + ae.y;
            a0 = LRELU(a0); a1 = LRELU(a1);
            w0 = expf(a0); w1 = expf(a1);
        }
        dp0 += w0; dp1 += w1;
        ws[w][c] = make_float4(w0, w1, __int_as_float(s), 0.f);
        // wave-private LDS; zero-weight-padded; 4 edges per sub-iter
        int cr = (cnt + 7) & ~7;
        for (int i = 0; i < cr; i += 8) {
#pragma unroll
            for (int u = 0; u < 2; ++u) {
                float4 p = ws[w][i + u * 4 + g];
                float wl = (lc < 8) ? p.x : p.y;
                uint4 q = *(const uint4*)&xrow[(long)__float_as_int(p.z) * 256];
                acc[0] += wl * bflo(q.x); acc[1] += wl * bfhi(q.x);
                acc[2] += wl * bflo(q.y); acc[3] += wl * bfhi(q.y);
                acc[4] += wl * bflo(q.z); acc[5] += wl * bfhi(q.z);
                acc[6] += wl * bflo(q.w); acc[7] += wl * bfhi(q.w);
            }
        }
    }
#pragma unroll
    for (int k = 32; k; k >>= 1) {
        dp0 += __shfl_xor(dp0, k, 64);
        dp1 += __shfl_xor(dp1, k, 64);
    }
    // fold the 4 edge-groups: lanes {g*16+lc} all end up with the col sums
#pragma unroll
    for (int j = 0; j < 8; ++j) {
        acc[j] += __shfl_xor(acc[j], 16, 64);
        acc[j] += __shfl_xor(acc[j], 32, 64);
    }
    // self term (added once, identically on all 4 dup groups)
    uint4 us = *(const uint4*)&xrow[(long)n * 256];
    float wself_l = (lc < 8) ? wself0 : wself1;
    acc[0] += wself_l * bflo(us.x); acc[1] += wself_l * bfhi(us.x);
    acc[2] += wself_l * bflo(us.y); acc[3] += wself_l * bfhi(us.y);
    acc[4] += wself_l * bflo(us.z); acc[5] += wself_l * bfhi(us.z);
    acc[6] += wself_l * bflo(us.w); acc[7] += wself_l * bfhi(us.w);
    float dsum = ((lc < 8) ? dp0 + wself0 : dp1 + wself1) + 1e-16f;
    float rd = 1.f / dsum;
    float4 r0 = *(const float4*)&io[(long)n * 256 + col0];
    float4 r1 = *(const float4*)&io[(long)n * 256 + col0 + 4];
    float v[8];
    v[0] = acc[0] * rd + r0.x; v[1] = acc[1] * rd + r0.y;
    v[2] = acc[2] * rd + r0.z; v[3] = acc[3] * rd + r0.w;
    v[4] = acc[4] * rd + r1.x; v[5] = acc[5] * rd + r1.y;
    v[6] = acc[6] * rd + r1.z; v[7] = acc[7] * rd + r1.w;
    float s1 = 0.f, s2 = 0.f;
#pragma unroll
    for (int j = 0; j < 8; ++j) { s1 += v[j]; s2 += v[j] * v[j]; }
#pragma unroll
    for (int k = 32; k; k >>= 1) {
        s1 += __shfl_xor(s1, k, 64);
        s2 += __shfl_xor(s2, k, 64);
    }
    if (c == 0) { red[w] = s1 * 0.25f; red[2 + w] = s2 * 0.25f; }
    __syncthreads();
    float mu = (red[0] + red[1]) * (1.f / 256.f);
    float var = (red[2] + red[3]) * (1.f / 256.f) - mu * mu;
    float rs = rsqrtf(var + 1e-5f);
    float4 lg0 = *(const float4*)&ln_g[col0];
    float4 lg1 = *(const float4*)&ln_g[col0 + 4];
    float4 lb0 = *(const float4*)&ln_b[col0];
    float4 lb1 = *(const float4*)&ln_b[col0 + 4];
    if (g == 0) {
        float4 y0, y1;
        y0.x = fmaxf((v[0] - mu) * rs * lg0.x + lb0.x, 0.f);
        y0.y = fmaxf((v[1] - mu) * rs * lg0.y + lb0.y, 0.f);
        y0.z = fmaxf((v[2] - mu) * rs * lg0.z + lb0.z, 0.f);
        y0.w = fmaxf((v[3] - mu) * rs * lg0.w + lb0.w, 0.f);
        y1.x = fmaxf((v[4] - mu) * rs * lg1.x + lb1.x, 0.f);
        y1.y = fmaxf((v[5] - mu) * rs * lg1.y + lb1.y, 0.f);
        y1.z = fmaxf((v[6] - mu) * rs * lg1.z + lb1.z, 0.f);
        y1.w = fmaxf((v[7] - mu) * rs * lg1.w + lb1.w, 0.f);
        *(float4*)&io[(long)n * 256 + col0] = y0;
        *(float4*)&io[(long)n * 256 + col0 + 4] = y1;
    }
}

// --------------------------------- GAT layer 2 (H=1, C=64): one wave per node
// Gather: 4 edges / iter, 16 lanes x dwordx2 (4 cols per lane).
__global__ __launch_bounds__(64) void k_gat2(
    const unsigned short* __restrict__ xs2b, const float* __restrict__ a_src,
    const float* __restrict__ a_dst, const int* __restrict__ row_off,
    const int* __restrict__ csr_pack,
    const int* __restrict__ cnt_t, const float* __restrict__ aet2,
    const float* __restrict__ ln_g, const float* __restrict__ ln_b,
    float* io)
{
    __shared__ __align__(8) float2 ws[64];
    __shared__ float aetl[4];
    int n = blockIdx.x;
    int c = threadIdx.x;
    int lc = c & 15, g = c >> 4;
    if (c < 4) aetl[c] = aet2[c];
    int off = row_off[n], deg = row_off[n + 1] - off;
    float a_d = a_dst[n];
    float ael = 0.f;
    int degc = 0;
#pragma unroll
    for (int ty = 0; ty < 4; ++ty) {
        int ct = cnt_t[n * 4 + ty];
        degc += ct;
        ael += (float)ct * aet2[ty];
    }
    ael *= (degc > 0 ? 1.f / (float)degc : 1.f);
    float al = a_src[n] + a_d + ael;
    al = LRELU(al);
    float wself = expf(al);

    int colb = lc * 4;                          // 4 cols per lane
    const unsigned short* xrow = xs2b + colb;   // + s*64 per gather
    float acc[4] = {0.f, 0.f, 0.f, 0.f};
    float dp = 0.f;
    for (int base = 0; base < deg; base += 64) {
        int cnt = min(64, deg - base);
        float we = 0.f;
        int s = 0;
        if (c < cnt) {
            int pk = csr_pack[off + base + c];
            s = pk & 0x0FFFFFFF;
            int ty = ((unsigned)pk) >> 28;
            float a = a_src[s] + a_d + aetl[ty];
            a = LRELU(a);
            we = expf(a);
        }
        dp += we;
        ws[c] = make_float2(we, __int_as_float(s));
        int cr = (cnt + 7) & ~7;
        for (int i = 0; i < cr; i += 8) {
#pragma unroll
            for (int u = 0; u < 2; ++u) {
                float2 p = ws[i + u * 4 + g];
                uint2 q = *(const uint2*)&xrow[(long)__float_as_int(p.y) * 64];
                acc[0] += p.x * bflo(q.x); acc[1] += p.x * bfhi(q.x);
                acc[2] += p.x * bflo(q.y); acc[3] += p.x * bfhi(q.y);
            }
        }
    }
#pragma unroll
    for (int k = 32; k; k >>= 1) dp += __shfl_xor(dp, k, 64);
#pragma unroll
    for (int j = 0; j < 4; ++j) {
        acc[j] += __shfl_xor(acc[j], 16, 64);
        acc[j] += __shfl_xor(acc[j], 32, 64);
    }
    uint2 us = *(const uint2*)&xrow[(long)n * 64];
    acc[0] += wself * bflo(us.x); acc[1] += wself * bfhi(us.x);
    acc[2] += wself * bflo(us.y); acc[3] += wself * bfhi(us.y);
    float dsum = dp + wself + 1e-16f;
    float rd = 1.f / dsum;
    float4 r = *(const float4*)&io[(long)n * 64 + colb];
    float v[4];
    v[0] = acc[0] * rd + r.x; v[1] = acc[1] * rd + r.y;
    v[2] = acc[2] * rd + r.z; v[3] = acc[3] * rd + r.w;
    float s1 = v[0] + v[1] + v[2] + v[3];
    float s2 = v[0] * v[0] + v[1] * v[1] + v[2] * v[2] + v[3] * v[3];
#pragma unroll
    for (int k = 32; k; k >>= 1) {
        s1 += __shfl_xor(s1, k, 64);
        s2 += __shfl_xor(s2, k, 64);
    }
    float mu = s1 * (1.f / 256.f);              // 4x dup: 64 lanes x 4 cols
    float var = s2 * (1.f / 256.f) - mu * mu;
    float rs = rsqrtf(var + 1e-5f);
    if (g == 0) {
        float4 lg = *(const float4*)&ln_g[colb];
        float4 lb = *(const float4*)&ln_b[colb];
        float4 y;
        y.x = (v[0] - mu) * rs * lg.x + lb.x;
        y.y = (v[1] - mu) * rs * lg.y + lb.y;
        y.z = (v[2] - mu) * rs * lg.z + lb.z;
        y.w = (v[3] - mu) * rs * lg.w + lb.w;
        *(float4*)&io[(long)n * 64 + colb] = y;
    }
}

// --------------------------------------------------------------- classifier
__global__ __launch_bounds__(256) void k_cls(
    const float* __restrict__ hid2, const int* __restrict__ asp,
    const float* __restrict__ w, const float* __restrict__ b,
    float* __restrict__ out)
{
    int g = blockIdx.x * 256 + threadIdx.x;
    int i = g / 3, j = g - i * 3;
    int a = asp[i];
    float acc = b[j];
#pragma unroll 8
    for (int cc = 0; cc < 64; ++cc) acc += hid2[(long)a * 64 + cc] * w[cc * 3 + j];
    out[i * 3 + j] = acc;
}

extern "C" void kernel_launch(void* const* d_in, const int* in_sizes, int n_in,
                              void* d_out, int out_size, void* d_ws, size_t ws_size,
                              hipStream_t stream)
{
    const float* features    = (const float*)d_in[0];
    const int*   edge_index  = (const int*)d_in[1];
    const int*   aspect      = (const int*)d_in[2];
    const int*   etypes      = (const int*)d_in[3];
    const int*   ntypes      = (const int*)d_in[4];
    const float* pos         = (const float*)d_in[5];
    const float* fe_w1       = (const float*)d_in[6];
    const float* fe_b1       = (const float*)d_in[7];
    const float* fe_w2       = (const float*)d_in[8];
    const float* fe_b2       = (const float*)d_in[9];
    const float* fe_pos_w    = (const float*)d_in[10];
    const float* fe_pos_b    = (const float*)d_in[11];
    const float* fe_type_emb = (const float*)d_in[12];
    const float* fe_out_w    = (const float*)d_in[13];
    const float* fe_out_b    = (const float*)d_in[14];
    const float* g1_lin_w    = (const float*)d_in[15];
    const float* g1_att_src  = (const float*)d_in[16];
    const float* g1_att_dst  = (const float*)d_in[17];
    const float* g1_edge_emb = (const float*)d_in[18];
    const float* g1_lin_edge = (const float*)d_in[19];
    const float* g1_att_edge = (const float*)d_in[20];
    const float* g1_bias     = (const float*)d_in[21];
    const float* g1_res_w    = (const float*)d_in[22];
    const float* g1_res_b    = (const float*)d_in[23];
    const float* g1_ln_g     = (const float*)d_in[24];
    const float* g1_ln_b     = (const float*)d_in[25];
    const float* g2_lin_w    = (const float*)d_in[26];
    const float* g2_att_src  = (const float*)d_in[27];
    const float* g2_att_dst  = (const float*)d_in[28];
    const float* g2_edge_emb = (const float*)d_in[29];
    const float* g2_lin_edge = (const float*)d_in[30];
    const float* g2_att_edge = (const float*)d_in[31];
    const float* g2_bias     = (const float*)d_in[32];
    const float* g2_res_w    = (const float*)d_in[33];
    const float* g2_res_b    = (const float*)d_in[34];
    const float* g2_ln_g     = (const float*)d_in[35];
    const float* g2_ln_b     = (const float*)d_in[36];
    const float* cls_w       = (const float*)d_in[37];
    const float* cls_b       = (const float*)d_in[38];

    const int N = in_sizes[0] / 768;   // 50000
    const int E = in_sizes[1] / 2;     // 800000
    const int* src = edge_index;
    const int* dst = edge_index + E;

    char* wsb = (char*)d_ws;
    size_t off = 0;
    auto alloc = [&](size_t bytes) -> char* {
        char* p = wsb + off;
        off += (bytes + 255) & ~(size_t)255;
        return p;
    };
    float* t1      = (float*)alloc((size_t)N * 64 * 4);
    float* hfe     = (float*)alloc((size_t)N * 64 * 4);
    unsigned short* xs1b = (unsigned short*)alloc((size_t)N * 256 * 2);
    unsigned short* xs2b = (unsigned short*)alloc((size_t)N * 64 * 2);
    float* rp1     = (float*)alloc((size_t)N * 256 * 4);  // res_pre1, then hid1
    float* rp2     = (float*)alloc((size_t)N * 64 * 4);   // res_pre2, then hid2
    float* a_src1  = (float*)alloc((size_t)N * 4 * 4);
    float* a_dst1  = (float*)alloc((size_t)N * 4 * 4);
    float* a_src2  = (float*)alloc((size_t)N * 4);
    float* a_dst2  = (float*)alloc((size_t)N * 4);
    int*   cnt_t   = (int*)alloc((size_t)N * 4 * 4);
    int*   row_off = (int*)alloc((size_t)(N + 1) * 4);
    int*   cursor  = (int*)alloc((size_t)N * 4);
    int*   blk     = (int*)alloc(1024);
    int*   csr_pack= (int*)alloc((size_t)E * 4);
    float* aet1    = (float*)alloc(64);
    float* aet2    = (float*)alloc(64);
    unsigned short* bz_fe1 = (unsigned short*)alloc(768 * 64 * 2);
    unsigned short* bz_p1  = (unsigned short*)alloc(64 * 512 * 2);
    unsigned short* bz_p2  = (unsigned short*)alloc(256 * 128 * 2);

    hipMemsetAsync(cnt_t, 0, (size_t)N * 4 * 4, stream);

    int mb = (N + 63) / 64;   // 782 row-tiles
    int ab = (N + 3) / 4;     // k_att blocks

    k_tables<<<1, 64, 0, stream>>>(g1_edge_emb, g1_lin_edge, g1_att_edge,
                                   g2_edge_emb, g2_lin_edge, g2_att_edge, aet1, aet2);
    k_bswz_fe1<<<48, 256, 0, stream>>>(fe_w1, bz_fe1);
    k_bswz2<64, 256><<<32, 256, 0, stream>>>(g1_lin_w, g1_res_w, bz_p1);
    k_bswz2<256, 64><<<32, 256, 0, stream>>>(g2_lin_w, g2_res_w, bz_p2);
    k_fe1<<<mb, 256, 0, stream>>>(features, bz_fe1, fe_b1, t1, N);
    k_fe2<<<N / 4, 256, 0, stream>>>(t1, fe_w2, fe_b2, ntypes, fe_type_emb, pos,
                                     fe_pos_w, fe_pos_b, fe_out_w, fe_out_b, hfe);
    k_prep_gemm<64, 256><<<dim3(mb, 4), 256, 0, stream>>>(
        hfe, bz_p1, g1_bias, g1_res_b, xs1b, rp1, N);
    k_att<4><<<ab, 256, 0, stream>>>(xs1b, g1_att_src, g1_att_dst, a_src1, a_dst1, N);
    int eblk = (E + 255) / 256;
    int nb = (N + 255) / 256;
    k_count<<<eblk, 256, 0, stream>>>(dst, etypes, cnt_t, E);
    k_scan1<<<nb, 256, 0, stream>>>(cnt_t, row_off, blk, N);
    k_scan2<<<1, 256, 0, stream>>>(blk, nb);
    k_scan3<<<nb, 256, 0, stream>>>(row_off, cursor, blk, N, E);
    k_scatter<<<eblk, 256, 0, stream>>>(src, dst, etypes, cursor, csr_pack, E);
    k_gat1<<<N, 128, 0, stream>>>(xs1b, a_src1, a_dst1, row_off, csr_pack,
                                  cnt_t, aet1, g1_ln_g, g1_ln_b, rp1);
    k_prep_gemm<256, 64><<<dim3(mb, 1), 256, 0, stream>>>(
        rp1, bz_p2, g2_bias, g2_res_b, xs2b, rp2, N);
    k_att<1><<<ab, 256, 0, stream>>>(xs2b, g2_att_src, g2_att_dst, a_src2, a_dst2, N);
    k_gat2<<<N, 64, 0, stream>>>(xs2b, a_src2, a_dst2, row_off, csr_pack,
                                 cnt_t, aet2, g2_ln_g, g2_ln_b, rp2);
    k_cls<<<(out_size + 255) / 256, 256, 0, stream>>>(rp2, aspect, cls_w, cls_b,
                                                      (float*)d_out);
}